// Round 2
// 336.098 us; speedup vs baseline: 1.1275x; 1.1275x over previous
//
#include <hip/hip_runtime.h>

#define N_NODES 100000
#define N_EDGES 800000
#define NF 81
#define NB 22
#define OC 64
#define SCAN_CHUNK 1024
#define SCAN_BLOCKS ((N_NODES + SCAN_CHUNK - 1) / SCAN_CHUNK)   // 98

typedef __attribute__((ext_vector_type(8))) short bf16x8;
typedef __attribute__((ext_vector_type(4))) float f32x4;

// round-to-nearest-even fp32 -> bf16 (high part), returns residual in rest
__device__ inline unsigned short bfsplit(float v, float& rest) {
    const unsigned b = __float_as_uint(v);
    const unsigned short h = (unsigned short)((b + 0x7fffu + ((b >> 16) & 1u)) >> 16);
    rest = v - __uint_as_float(((unsigned)h) << 16);
    return h;
}

// ---------------------------------------------------------------------------
// Build B^T in bf16 hi/lo: BT[c][k], c in [0,128), k in [0,96).
// c<64 -> w_s column c ; c>=64 -> w_n column c-64 (first 81 rows). k>=81 -> 0.
// Written into scratch aliasing the head of the rec region (stream-ordered:
// k_prep overwrites rec only after k_node_mfma has consumed B^T).
__global__ void k_wprep(const float* __restrict__ w_s, const float* __restrict__ w_n,
                        short* __restrict__ bt)
{
    const int tid = blockIdx.x * blockDim.x + threadIdx.x;
    if (tid >= 128 * 96) return;
    const int c = tid / 96;
    const int k = tid - c * 96;
    float v = 0.f;
    if (k < NF) v = (c < OC) ? w_s[k * OC + c] : w_n[k * OC + (c - OC)];
    float rest, dummy;
    const unsigned short h = bfsplit(v, rest);
    const unsigned short l = bfsplit(rest, dummy);
    bt[c * 96 + k]               = (short)h;          // BT_hi
    bt[128 * 96 + c * 96 + k]    = (short)l;          // BT_lo
}

// ---------------------------------------------------------------------------
// Node GEMM on matrix cores: [out | pb] = feat @ [w_s | w_n[:81]]
// Split-bf16 3-pass MFMA (Ah*Bh + Ah*Bl + Al*Bh) -> ~2^-17 relative error.
// Block: 64 nodes x 128 cols, 4 waves; wave w owns cols [w*32, w*32+32).
// A staged in LDS bf16 hi/lo, row stride 104 (16B aligned, bank-step 20).
// B frags (12 x bf16x8 = 48 VGPR) loaded once per block from global B^T.
__global__ __launch_bounds__(256) void k_node_mfma(
    const float* __restrict__ feat, const short* __restrict__ bt,
    float* __restrict__ out, float* __restrict__ pb, float4* __restrict__ xyz)
{
    __shared__ short shA[2 * 64 * 104];               // hi at 0, lo at 6656 (26.6 KB)
    const int t    = threadIdx.x;
    const int lane = t & 63;
    const int w    = t >> 6;
    const int n0   = blockIdx.x * 64;

    // ---- B fragments from global B^T (L2-resident, 16B-aligned b128 loads)
    const int krow = (lane >> 4) * 8;                 // k offset within 32-k tile
    bf16x8 Bh[3][2], Bl[3][2];
#pragma unroll
    for (int kt = 0; kt < 3; ++kt)
#pragma unroll
        for (int c = 0; c < 2; ++c) {
            const int col = w * 32 + c * 16 + (lane & 15);
            const int off = col * 96 + kt * 32 + krow;
            Bh[kt][c] = *(const bf16x8*)(bt + off);
            Bl[kt][c] = *(const bf16x8*)(bt + 128 * 96 + off);
        }

    // ---- stage A (64 rows x 81 k) as bf16 hi/lo into LDS
    const long gbase = (long)n0 * NF;
    const long gmax  = (long)N_NODES * NF;
    for (int j = t; j < (64 * NF) / 4; j += 256) {    // 1296 float4s
        const int flat = j * 4;
        float v[4];
        if (gbase + flat + 3 < gmax) {
            const float4 q = *(const float4*)(feat + gbase + flat);
            v[0] = q.x; v[1] = q.y; v[2] = q.z; v[3] = q.w;
        } else {
#pragma unroll
            for (int i = 0; i < 4; ++i)
                v[i] = (gbase + flat + i < gmax) ? feat[gbase + flat + i] : 0.f;
        }
#pragma unroll
        for (int i = 0; i < 4; ++i) {
            const int fi  = flat + i;
            const int row = (int)((unsigned)fi / 81u);
            const int k   = fi - row * 81;
            float rest, dummy;
            const unsigned short h = bfsplit(v[i], rest);
            const unsigned short l = bfsplit(rest, dummy);
            shA[row * 104 + k]        = (short)h;
            shA[6656 + row * 104 + k] = (short)l;
        }
    }
    // zero K padding 81..96 (frags read up to k=95)
    for (int j = t; j < 64 * 16; j += 256) {
        const int row = j >> 4, k = NF + (j & 15);
        shA[row * 104 + k] = 0;
        shA[6656 + row * 104 + k] = 0;
    }

    // xyz in exact fp32 (distance path must stay fp32-accurate)
    if (t < 64 && n0 + t < N_NODES) {
        const float* fp = feat + (long)(n0 + t) * NF;
        xyz[n0 + t] = make_float4(fp[0], fp[1], fp[2], 0.f);
    }
    __syncthreads();

    // ---- MFMA: 4 row-tiles x 2 col-tiles x 3 k-tiles x 3 passes
    f32x4 acc[4][2];
#pragma unroll
    for (int rt = 0; rt < 4; ++rt)
#pragma unroll
        for (int c = 0; c < 2; ++c)
            acc[rt][c] = (f32x4){0.f, 0.f, 0.f, 0.f};

#pragma unroll
    for (int kt = 0; kt < 3; ++kt) {
        bf16x8 Ah[4], Al[4];
#pragma unroll
        for (int rt = 0; rt < 4; ++rt) {
            const int o = (rt * 16 + (lane & 15)) * 104 + kt * 32 + krow;
            Ah[rt] = *(const bf16x8*)(shA + o);
            Al[rt] = *(const bf16x8*)(shA + 6656 + o);
        }
#pragma unroll
        for (int rt = 0; rt < 4; ++rt)
#pragma unroll
            for (int c = 0; c < 2; ++c) {
                f32x4 a = acc[rt][c];
                a = __builtin_amdgcn_mfma_f32_16x16x32_bf16(Ah[rt], Bh[kt][c], a, 0, 0, 0);
                a = __builtin_amdgcn_mfma_f32_16x16x32_bf16(Ah[rt], Bl[kt][c], a, 0, 0, 0);
                a = __builtin_amdgcn_mfma_f32_16x16x32_bf16(Al[rt], Bh[kt][c], a, 0, 0, 0);
                acc[rt][c] = a;
            }
    }

    // ---- epilogue: D layout col=lane&15, row=(lane>>4)*4+reg (verified map)
    const int c0    = w * 32 + (lane & 15);
    float* db       = (w < 2) ? out : pb;
    const int cbase = (w < 2) ? c0 : c0 - OC;
    const int r0    = (lane >> 4) * 4;
#pragma unroll
    for (int rt = 0; rt < 4; ++rt)
#pragma unroll
        for (int c = 0; c < 2; ++c)
#pragma unroll
            for (int reg = 0; reg < 4; ++reg) {
                const int node = n0 + rt * 16 + r0 + reg;
                if (node < N_NODES)
                    db[(long)node * OC + cbase + c * 16] = acc[rt][c][reg];
            }
}

// ---------------------------------------------------------------------------
__global__ void k_hist(const int* __restrict__ src, int* __restrict__ cnt) {
    const int e = blockIdx.x * blockDim.x + threadIdx.x;
    if (e < N_EDGES) atomicAdd(&cnt[src[e]], 1);
}

__global__ __launch_bounds__(256) void k_scan_blk(
    const int* __restrict__ cnt, int* __restrict__ row, int* __restrict__ bsum)
{
    __shared__ int sh[256];
    const int t = threadIdx.x;
    const int base = blockIdx.x * SCAN_CHUNK + t * 4;
    int c0 = 0, c1 = 0, c2 = 0, c3 = 0;
    if (base + 3 < N_NODES) {
        const int4 c = *(const int4*)(cnt + base);
        c0 = c.x; c1 = c.y; c2 = c.z; c3 = c.w;
    } else {
        if (base + 0 < N_NODES) c0 = cnt[base + 0];
        if (base + 1 < N_NODES) c1 = cnt[base + 1];
        if (base + 2 < N_NODES) c2 = cnt[base + 2];
    }
    const int s = c0 + c1 + c2 + c3;
    sh[t] = s;
    __syncthreads();
    for (int off = 1; off < 256; off <<= 1) {
        int v = sh[t];
        int a = (t >= off) ? sh[t - off] : 0;
        __syncthreads();
        sh[t] = v + a;
        __syncthreads();
    }
    const int excl = sh[t] - s;
    if (t == 255) bsum[blockIdx.x] = sh[255];
    if (base + 3 < N_NODES) {
        int4 r;
        r.x = excl; r.y = excl + c0; r.z = excl + c0 + c1; r.w = excl + c0 + c1 + c2;
        *(int4*)(row + base) = r;
    } else {
        int e = excl;
        if (base + 0 < N_NODES) { row[base + 0] = e; e += c0; }
        if (base + 1 < N_NODES) { row[base + 1] = e; e += c1; }
        if (base + 2 < N_NODES) { row[base + 2] = e; }
    }
}

__global__ void k_scan_top(int* __restrict__ bsum, int* __restrict__ row) {
    __shared__ int sh[128];
    const int t = threadIdx.x;
    const int v = (t < SCAN_BLOCKS) ? bsum[t] : 0;
    sh[t] = v;
    __syncthreads();
    for (int off = 1; off < 128; off <<= 1) {
        int x = sh[t];
        int a = (t >= off) ? sh[t - off] : 0;
        __syncthreads();
        sh[t] = x + a;
        __syncthreads();
    }
    if (t < SCAN_BLOCKS) bsum[t] = sh[t] - v;
    if (t == 127) row[N_NODES] = sh[127];
}

__global__ __launch_bounds__(256) void k_scan_add(
    int* __restrict__ row, int* __restrict__ cursor, const int* __restrict__ bsum)
{
    const int off = bsum[blockIdx.x];
    const int base = blockIdx.x * SCAN_CHUNK + threadIdx.x * 4;
    if (base + 3 < N_NODES) {
        int4 r = *(const int4*)(row + base);
        r.x += off; r.y += off; r.z += off; r.w += off;
        *(int4*)(row + base) = r;
        *(int4*)(cursor + base) = r;
    } else {
#pragma unroll
        for (int k = 0; k < 4; ++k)
            if (base + k < N_NODES) {
                const int v = row[base + k] + off;
                row[base + k] = v;
                cursor[base + k] = v;
            }
    }
}

// ---------------------------------------------------------------------------
// Scatter one 64B record per edge into src-sorted slot:
//  dw[0..10]  = bond[0..21] packed as bf16 pairs (RNE-ish bias)
//  dw[11]     = inv (f32)          dw[12] = dst id        dw[13..15] unused
__device__ inline unsigned pk_bf16(float a, float b) {
    const unsigned ua = (__float_as_uint(a) + 0x8000u) >> 16;
    const unsigned ub = (__float_as_uint(b) + 0x8000u) & 0xffff0000u;
    return ua | ub;
}

__global__ void k_prep(const int* __restrict__ src, const int* __restrict__ dst,
                       const float* __restrict__ bond, const float4* __restrict__ xyz,
                       int* __restrict__ cursor, unsigned* __restrict__ rec)
{
    const int e = blockIdx.x * blockDim.x + threadIdx.x;
    if (e >= N_EDGES) return;
    const int s = src[e];
    const int d = dst[e];
    const float4 a = xyz[s], b = xyz[d];
    const float dx = a.x - b.x, dy = a.y - b.y, dz = a.z - b.z;
    const float d2 = dx * dx + dy * dy + dz * dz;
    const float inv = (d2 > 0.f) ? __builtin_amdgcn_rcpf(d2) : 1.0e4f;

    float bv[NB];
    const float2* bp = (const float2*)(bond + (long)e * NB);   // 88B, 8B-aligned
#pragma unroll
    for (int j = 0; j < NB / 2; ++j) {
        const float2 v = bp[j];
        bv[2 * j] = v.x; bv[2 * j + 1] = v.y;
    }

    unsigned p[11];
#pragma unroll
    for (int j = 0; j < 11; ++j) p[j] = pk_bf16(bv[2 * j], bv[2 * j + 1]);

    const int pos = atomicAdd(&cursor[s], 1);
    unsigned* r = rec + (size_t)pos * 16;
    *(uint4*)(r)     = make_uint4(p[0], p[1], p[2], p[3]);
    *(uint4*)(r + 4) = make_uint4(p[4], p[5], p[6], p[7]);
    *(uint4*)(r + 8) = make_uint4(p[8], p[9], p[10], __float_as_uint(inv));
    *(uint2*)(r + 12) = make_uint2((unsigned)d, 0u);
}

// ---------------------------------------------------------------------------
// Gather: wave per node, lane = channel, NO atomics.
__global__ __launch_bounds__(256) void k_gather(
    const int* __restrict__ row, const unsigned* __restrict__ rec,
    const float* __restrict__ w_n, const float* __restrict__ pb,
    const float4* __restrict__ xyz, float* __restrict__ out)
{
    const int lane = threadIdx.x & 63;
    const int wid  = (int)((blockIdx.x * blockDim.x + threadIdx.x) >> 6);
    if (wid >= N_NODES) return;
    const int n = __builtin_amdgcn_readfirstlane(wid);

    float wnb[NB];
#pragma unroll
    for (int j = 0; j < NB; ++j) wnb[j] = w_n[(NF + j) * OC + lane];
    const float w0 = w_n[0 * OC + lane];
    const float w1 = w_n[1 * OC + lane];
    const float w2 = w_n[2 * OC + lane];

    const int rs = row[n], re = row[n + 1];
    const float4 xs = xyz[n];
    const float pa = pb[(long)n * OC + lane]
                   - (xs.x * w0 + xs.y * w1 + xs.z * w2);

    float acc = 0.f;
    int i = rs;
    for (; i + 2 <= re; i += 2) {
        const unsigned* rA = rec + (size_t)i * 16;
        const unsigned* rB = rA + 16;
        unsigned pA[13], pB[13];
#pragma unroll
        for (int j = 0; j < 13; ++j) pA[j] = rA[j];   // s_load batch
#pragma unroll
        for (int j = 0; j < 13; ++j) pB[j] = rB[j];
        const float invA = __uint_as_float(pA[11]);
        const float invB = __uint_as_float(pB[11]);
        const int   tA   = (int)pA[12];
        const int   tB   = (int)pB[12];
        const float pbtA = pb[(long)tA * OC + lane];
        const float pbtB = pb[(long)tB * OC + lane];

        float cA = invA * (pa + pbtA);
        float cB = invB * (pa + pbtB);
#pragma unroll
        for (int j = 0; j < 11; ++j) {
            cA += __uint_as_float(pA[j] << 16)        * wnb[2 * j]
                + __uint_as_float(pA[j] & 0xffff0000u) * wnb[2 * j + 1];
            cB += __uint_as_float(pB[j] << 16)        * wnb[2 * j]
                + __uint_as_float(pB[j] & 0xffff0000u) * wnb[2 * j + 1];
        }
        acc += cA + cB;
    }
    if (i < re) {   // tail edge
        const unsigned* r = rec + (size_t)i * 16;
        unsigned p[13];
#pragma unroll
        for (int j = 0; j < 13; ++j) p[j] = r[j];
        const float inv = __uint_as_float(p[11]);
        const int   tt  = (int)p[12];
        const float pbt = pb[(long)tt * OC + lane];
        float c = inv * (pa + pbt);
#pragma unroll
        for (int j = 0; j < 11; ++j)
            c += __uint_as_float(p[j] << 16)        * wnb[2 * j]
               + __uint_as_float(p[j] & 0xffff0000u) * wnb[2 * j + 1];
        acc += c;
    }

    out[(long)n * OC + lane] += acc;
}

// ---------------------------------------------------------------------------
extern "C" void kernel_launch(void* const* d_in, const int* in_sizes, int n_in,
                              void* d_out, int out_size, void* d_ws, size_t ws_size,
                              hipStream_t stream) {
    const float* feat = (const float*)d_in[0];
    const float* bond = (const float*)d_in[1];
    const float* w_s  = (const float*)d_in[2];
    const float* w_n  = (const float*)d_in[3];
    const int*   src  = (const int*)d_in[4];
    const int*   dstv = (const int*)d_in[5];
    float* out = (float*)d_out;

    // workspace layout (64B-aligned), ~79.6 MB total
    char* base = (char*)d_ws;
    float*    pb     = (float*)   (base);                 // 25,600,000
    float4*   xyz    = (float4*)  (base + 25600000);      //  1,600,000
    int*      row    = (int*)     (base + 27200000);      //    400,016
    int*      cnt    = (int*)     (base + 27600016);      //    400,000
    int*      cursor = (int*)     (base + 28000016);      //    400,000
    int*      bsum   = (int*)     (base + 28400016);      //        560 (pad)
    unsigned* rec    = (unsigned*)(base + 28400576);      // 51,200,000
    // B^T bf16 hi/lo scratch aliases the head of rec (49,152 B).
    // Safe: k_node_mfma (reader) completes before k_prep (writer) on the stream.
    short*    btw    = (short*)rec;

    hipMemsetAsync(cnt, 0, N_NODES * sizeof(int), stream);

    k_wprep   <<<48, 256, 0, stream>>>(w_s, w_n, btw);
    k_node_mfma<<<(N_NODES + 63) / 64, 256, 0, stream>>>(feat, btw, out, pb, xyz);
    k_hist    <<<(N_EDGES + 255) / 256, 256, 0, stream>>>(src, cnt);
    k_scan_blk<<<SCAN_BLOCKS, 256, 0, stream>>>(cnt, row, bsum);
    k_scan_top<<<1, 128, 0, stream>>>(bsum, row);
    k_scan_add<<<SCAN_BLOCKS, 256, 0, stream>>>(row, cursor, bsum);
    k_prep    <<<(N_EDGES + 255) / 256, 256, 0, stream>>>(src, dstv, bond, xyz,
                                                          cursor, rec);
    k_gather  <<<(N_NODES * 64 + 255) / 256, 256, 0, stream>>>(row, rec, w_n, pb,
                                                               xyz, out);
}

// Round 3
// 326.167 us; speedup vs baseline: 1.1619x; 1.0304x over previous
//
#include <hip/hip_runtime.h>

#define N_NODES 100000
#define N_EDGES 800000
#define NF 81
#define NB 22
#define OC 64
#define SCAN_CHUNK 1024
#define SCAN_BLOCKS ((N_NODES + SCAN_CHUNK - 1) / SCAN_CHUNK)   // 98

typedef __attribute__((ext_vector_type(8))) short bf16x8;
typedef __attribute__((ext_vector_type(4))) float f32x4;

#if defined(__has_builtin)
#if __has_builtin(__builtin_amdgcn_fdot2_f32_bf16)
#define HAVE_FDOT2 1
#endif
#endif

#ifdef HAVE_FDOT2
typedef __attribute__((ext_vector_type(2))) __bf16 bfv2;
#endif

// dot2: c += lo(a)*lo(b) + hi(a)*hi(b), operands are packed bf16 pairs
__device__ inline float dot2b(unsigned a, unsigned b, float c) {
#ifdef HAVE_FDOT2
    return __builtin_amdgcn_fdot2_f32_bf16(__builtin_bit_cast(bfv2, a),
                                           __builtin_bit_cast(bfv2, b), c, false);
#else
    return c + __uint_as_float(a << 16)         * __uint_as_float(b << 16)
             + __uint_as_float(a & 0xffff0000u) * __uint_as_float(b & 0xffff0000u);
#endif
}

// round-to-nearest-even fp32 -> bf16 (high part), returns residual in rest
__device__ inline unsigned short bfsplit(float v, float& rest) {
    const unsigned b = __float_as_uint(v);
    const unsigned short h = (unsigned short)((b + 0x7fffu + ((b >> 16) & 1u)) >> 16);
    rest = v - __uint_as_float(((unsigned)h) << 16);
    return h;
}

// ---------------------------------------------------------------------------
// Build B^T in bf16 hi/lo: BT[c][k], c in [0,128), k in [0,96).
// c<64 -> w_s column c ; c>=64 -> w_n column c-64 (first 81 rows). k>=81 -> 0.
// Written into scratch aliasing the head of the rec region (stream-ordered:
// k_prep overwrites rec only after k_node_mfma has consumed B^T).
__global__ void k_wprep(const float* __restrict__ w_s, const float* __restrict__ w_n,
                        short* __restrict__ bt)
{
    const int tid = blockIdx.x * blockDim.x + threadIdx.x;
    if (tid >= 128 * 96) return;
    const int c = tid / 96;
    const int k = tid - c * 96;
    float v = 0.f;
    if (k < NF) v = (c < OC) ? w_s[k * OC + c] : w_n[k * OC + (c - OC)];
    float rest, dummy;
    const unsigned short h = bfsplit(v, rest);
    const unsigned short l = bfsplit(rest, dummy);
    bt[c * 96 + k]               = (short)h;          // BT_hi
    bt[128 * 96 + c * 96 + k]    = (short)l;          // BT_lo
}

// ---------------------------------------------------------------------------
// Node GEMM on matrix cores: [out | pb] = feat @ [w_s | w_n[:81]]
// Split-bf16 3-pass MFMA (Ah*Bh + Ah*Bl + Al*Bh) -> ~2^-17 relative error.
// Block: 64 nodes x 128 cols, 4 waves; wave w owns cols [w*32, w*32+32).
__global__ __launch_bounds__(256) void k_node_mfma(
    const float* __restrict__ feat, const short* __restrict__ bt,
    float* __restrict__ out, float* __restrict__ pb, float4* __restrict__ xyz)
{
    __shared__ short shA[2 * 64 * 104];               // hi at 0, lo at 6656 (26.6 KB)
    const int t    = threadIdx.x;
    const int lane = t & 63;
    const int w    = t >> 6;
    const int n0   = blockIdx.x * 64;

    // ---- B fragments from global B^T (L2-resident, 16B-aligned b128 loads)
    const int krow = (lane >> 4) * 8;                 // k offset within 32-k tile
    bf16x8 Bh[3][2], Bl[3][2];
#pragma unroll
    for (int kt = 0; kt < 3; ++kt)
#pragma unroll
        for (int c = 0; c < 2; ++c) {
            const int col = w * 32 + c * 16 + (lane & 15);
            const int off = col * 96 + kt * 32 + krow;
            Bh[kt][c] = *(const bf16x8*)(bt + off);
            Bl[kt][c] = *(const bf16x8*)(bt + 128 * 96 + off);
        }

    // ---- stage A (64 rows x 81 k) as bf16 hi/lo into LDS
    const long gbase = (long)n0 * NF;
    const long gmax  = (long)N_NODES * NF;
    for (int j = t; j < (64 * NF) / 4; j += 256) {    // 1296 float4s
        const int flat = j * 4;
        float v[4];
        if (gbase + flat + 3 < gmax) {
            const float4 q = *(const float4*)(feat + gbase + flat);
            v[0] = q.x; v[1] = q.y; v[2] = q.z; v[3] = q.w;
        } else {
#pragma unroll
            for (int i = 0; i < 4; ++i)
                v[i] = (gbase + flat + i < gmax) ? feat[gbase + flat + i] : 0.f;
        }
#pragma unroll
        for (int i = 0; i < 4; ++i) {
            const int fi  = flat + i;
            const int row = (int)((unsigned)fi / 81u);
            const int k   = fi - row * 81;
            float rest, dummy;
            const unsigned short h = bfsplit(v[i], rest);
            const unsigned short l = bfsplit(rest, dummy);
            shA[row * 104 + k]        = (short)h;
            shA[6656 + row * 104 + k] = (short)l;
        }
    }
    // zero K padding 81..96 (frags read up to k=95)
    for (int j = t; j < 64 * 16; j += 256) {
        const int row = j >> 4, k = NF + (j & 15);
        shA[row * 104 + k] = 0;
        shA[6656 + row * 104 + k] = 0;
    }

    // xyz in exact fp32 (distance path must stay fp32-accurate)
    if (t < 64 && n0 + t < N_NODES) {
        const float* fp = feat + (long)(n0 + t) * NF;
        xyz[n0 + t] = make_float4(fp[0], fp[1], fp[2], 0.f);
    }
    __syncthreads();

    // ---- MFMA: 4 row-tiles x 2 col-tiles x 3 k-tiles x 3 passes
    f32x4 acc[4][2];
#pragma unroll
    for (int rt = 0; rt < 4; ++rt)
#pragma unroll
        for (int c = 0; c < 2; ++c)
            acc[rt][c] = (f32x4){0.f, 0.f, 0.f, 0.f};

#pragma unroll
    for (int kt = 0; kt < 3; ++kt) {
        bf16x8 Ah[4], Al[4];
#pragma unroll
        for (int rt = 0; rt < 4; ++rt) {
            const int o = (rt * 16 + (lane & 15)) * 104 + kt * 32 + krow;
            Ah[rt] = *(const bf16x8*)(shA + o);
            Al[rt] = *(const bf16x8*)(shA + 6656 + o);
        }
#pragma unroll
        for (int rt = 0; rt < 4; ++rt)
#pragma unroll
            for (int c = 0; c < 2; ++c) {
                f32x4 a = acc[rt][c];
                a = __builtin_amdgcn_mfma_f32_16x16x32_bf16(Ah[rt], Bh[kt][c], a, 0, 0, 0);
                a = __builtin_amdgcn_mfma_f32_16x16x32_bf16(Ah[rt], Bl[kt][c], a, 0, 0, 0);
                a = __builtin_amdgcn_mfma_f32_16x16x32_bf16(Al[rt], Bh[kt][c], a, 0, 0, 0);
                acc[rt][c] = a;
            }
    }

    // ---- epilogue: D layout col=lane&15, row=(lane>>4)*4+reg (verified map)
    const int c0    = w * 32 + (lane & 15);
    float* db       = (w < 2) ? out : pb;
    const int cbase = (w < 2) ? c0 : c0 - OC;
    const int r0    = (lane >> 4) * 4;
#pragma unroll
    for (int rt = 0; rt < 4; ++rt)
#pragma unroll
        for (int c = 0; c < 2; ++c)
#pragma unroll
            for (int reg = 0; reg < 4; ++reg) {
                const int node = n0 + rt * 16 + r0 + reg;
                if (node < N_NODES)
                    db[(long)node * OC + cbase + c * 16] = acc[rt][c][reg];
            }
}

// ---------------------------------------------------------------------------
__global__ void k_hist(const int* __restrict__ src, int* __restrict__ cnt) {
    const int e = blockIdx.x * blockDim.x + threadIdx.x;
    if (e < N_EDGES) atomicAdd(&cnt[src[e]], 1);
}

__global__ __launch_bounds__(256) void k_scan_blk(
    const int* __restrict__ cnt, int* __restrict__ row, int* __restrict__ bsum)
{
    __shared__ int sh[256];
    const int t = threadIdx.x;
    const int base = blockIdx.x * SCAN_CHUNK + t * 4;
    int c0 = 0, c1 = 0, c2 = 0, c3 = 0;
    if (base + 3 < N_NODES) {
        const int4 c = *(const int4*)(cnt + base);
        c0 = c.x; c1 = c.y; c2 = c.z; c3 = c.w;
    } else {
        if (base + 0 < N_NODES) c0 = cnt[base + 0];
        if (base + 1 < N_NODES) c1 = cnt[base + 1];
        if (base + 2 < N_NODES) c2 = cnt[base + 2];
    }
    const int s = c0 + c1 + c2 + c3;
    sh[t] = s;
    __syncthreads();
    for (int off = 1; off < 256; off <<= 1) {
        int v = sh[t];
        int a = (t >= off) ? sh[t - off] : 0;
        __syncthreads();
        sh[t] = v + a;
        __syncthreads();
    }
    const int excl = sh[t] - s;
    if (t == 255) bsum[blockIdx.x] = sh[255];
    if (base + 3 < N_NODES) {
        int4 r;
        r.x = excl; r.y = excl + c0; r.z = excl + c0 + c1; r.w = excl + c0 + c1 + c2;
        *(int4*)(row + base) = r;
    } else {
        int e = excl;
        if (base + 0 < N_NODES) { row[base + 0] = e; e += c0; }
        if (base + 1 < N_NODES) { row[base + 1] = e; e += c1; }
        if (base + 2 < N_NODES) { row[base + 2] = e; }
    }
}

__global__ void k_scan_top(int* __restrict__ bsum, int* __restrict__ row) {
    __shared__ int sh[128];
    const int t = threadIdx.x;
    const int v = (t < SCAN_BLOCKS) ? bsum[t] : 0;
    sh[t] = v;
    __syncthreads();
    for (int off = 1; off < 128; off <<= 1) {
        int x = sh[t];
        int a = (t >= off) ? sh[t - off] : 0;
        __syncthreads();
        sh[t] = x + a;
        __syncthreads();
    }
    if (t < SCAN_BLOCKS) bsum[t] = sh[t] - v;
    if (t == 127) row[N_NODES] = sh[127];
}

__global__ __launch_bounds__(256) void k_scan_add(
    int* __restrict__ row, int* __restrict__ cursor, const int* __restrict__ bsum)
{
    const int off = bsum[blockIdx.x];
    const int base = blockIdx.x * SCAN_CHUNK + threadIdx.x * 4;
    if (base + 3 < N_NODES) {
        int4 r = *(const int4*)(row + base);
        r.x += off; r.y += off; r.z += off; r.w += off;
        *(int4*)(row + base) = r;
        *(int4*)(cursor + base) = r;
    } else {
#pragma unroll
        for (int k = 0; k < 4; ++k)
            if (base + k < N_NODES) {
                const int v = row[base + k] + off;
                row[base + k] = v;
                cursor[base + k] = v;
            }
    }
}

// ---------------------------------------------------------------------------
// Scatter one 64B record per edge into src-sorted slot:
//  dw[0..10]  = bond[0..21] packed as bf16 pairs (RNE-ish bias)
//  dw[11]     = inv (f32)          dw[12] = dst id        dw[13..15] unused
__device__ inline unsigned pk_bf16(float a, float b) {
    const unsigned ua = (__float_as_uint(a) + 0x8000u) >> 16;
    const unsigned ub = (__float_as_uint(b) + 0x8000u) & 0xffff0000u;
    return ua | ub;
}

__global__ void k_prep(const int* __restrict__ src, const int* __restrict__ dst,
                       const float* __restrict__ bond, const float4* __restrict__ xyz,
                       int* __restrict__ cursor, unsigned* __restrict__ rec)
{
    const int e = blockIdx.x * blockDim.x + threadIdx.x;
    if (e >= N_EDGES) return;
    const int s = src[e];
    const int d = dst[e];
    const float4 a = xyz[s], b = xyz[d];
    const float dx = a.x - b.x, dy = a.y - b.y, dz = a.z - b.z;
    const float d2 = dx * dx + dy * dy + dz * dz;
    const float inv = (d2 > 0.f) ? __builtin_amdgcn_rcpf(d2) : 1.0e4f;

    float bv[NB];
    const float2* bp = (const float2*)(bond + (long)e * NB);   // 88B, 8B-aligned
#pragma unroll
    for (int j = 0; j < NB / 2; ++j) {
        const float2 v = bp[j];
        bv[2 * j] = v.x; bv[2 * j + 1] = v.y;
    }

    unsigned p[11];
#pragma unroll
    for (int j = 0; j < 11; ++j) p[j] = pk_bf16(bv[2 * j], bv[2 * j + 1]);

    const int pos = atomicAdd(&cursor[s], 1);
    unsigned* r = rec + (size_t)pos * 16;
    *(uint4*)(r)     = make_uint4(p[0], p[1], p[2], p[3]);
    *(uint4*)(r + 4) = make_uint4(p[4], p[5], p[6], p[7]);
    *(uint4*)(r + 8) = make_uint4(p[8], p[9], p[10], __float_as_uint(inv));
    *(uint2*)(r + 12) = make_uint2((unsigned)d, 0u);
}

// ---------------------------------------------------------------------------
// Gather: wave per node, lane = channel, NO atomics.
// v3: 4-edge unroll (4 record batches + 4 independent pb gathers in flight)
//     + bond contribution via v_dot2_f32_bf16 (weights packed bf16 at init).
__global__ __launch_bounds__(256) void k_gather(
    const int* __restrict__ row, const unsigned* __restrict__ rec,
    const float* __restrict__ w_n, const float* __restrict__ pb,
    const float4* __restrict__ xyz, float* __restrict__ out)
{
    const int lane = threadIdx.x & 63;
    const int wid  = (int)((blockIdx.x * blockDim.x + threadIdx.x) >> 6);
    if (wid >= N_NODES) return;
    const int n = __builtin_amdgcn_readfirstlane(wid);

    // per-lane w_n bond columns, packed as bf16 pairs (matches record packing)
    unsigned wp[11];
#pragma unroll
    for (int j = 0; j < 11; ++j)
        wp[j] = pk_bf16(w_n[(NF + 2 * j) * OC + lane],
                        w_n[(NF + 2 * j + 1) * OC + lane]);
    const float w0 = w_n[0 * OC + lane];
    const float w1 = w_n[1 * OC + lane];
    const float w2 = w_n[2 * OC + lane];

    const int rs = row[n], re = row[n + 1];
    const float4 xs = xyz[n];
    const float pa = pb[(long)n * OC + lane]
                   - (xs.x * w0 + xs.y * w1 + xs.z * w2);

    float acc = 0.f;
    int i = rs;

    // ---- main loop: 4 edges in flight
    for (; i + 4 <= re; i += 4) {
        unsigned P[4][13];
#pragma unroll
        for (int u = 0; u < 4; ++u) {
            const unsigned* r = rec + (size_t)(i + u) * 16;
#pragma unroll
            for (int j = 0; j < 13; ++j) P[u][j] = r[j];
        }
        float pbt[4];
#pragma unroll
        for (int u = 0; u < 4; ++u)
            pbt[u] = pb[(long)(int)P[u][12] * OC + lane];
        float c[4];
#pragma unroll
        for (int u = 0; u < 4; ++u)
            c[u] = __uint_as_float(P[u][11]) * (pa + pbt[u]);
#pragma unroll
        for (int j = 0; j < 11; ++j)
#pragma unroll
            for (int u = 0; u < 4; ++u)
                c[u] = dot2b(P[u][j], wp[j], c[u]);
        acc += (c[0] + c[1]) + (c[2] + c[3]);
    }

    // ---- tail: one edge at a time
    for (; i < re; ++i) {
        const unsigned* r = rec + (size_t)i * 16;
        unsigned p[13];
#pragma unroll
        for (int j = 0; j < 13; ++j) p[j] = r[j];
        const float pbt = pb[(long)(int)p[12] * OC + lane];
        float c = __uint_as_float(p[11]) * (pa + pbt);
#pragma unroll
        for (int j = 0; j < 11; ++j)
            c = dot2b(p[j], wp[j], c);
        acc += c;
    }

    out[(long)n * OC + lane] += acc;
}

// ---------------------------------------------------------------------------
extern "C" void kernel_launch(void* const* d_in, const int* in_sizes, int n_in,
                              void* d_out, int out_size, void* d_ws, size_t ws_size,
                              hipStream_t stream) {
    const float* feat = (const float*)d_in[0];
    const float* bond = (const float*)d_in[1];
    const float* w_s  = (const float*)d_in[2];
    const float* w_n  = (const float*)d_in[3];
    const int*   src  = (const int*)d_in[4];
    const int*   dstv = (const int*)d_in[5];
    float* out = (float*)d_out;

    // workspace layout (64B-aligned), ~79.6 MB total
    char* base = (char*)d_ws;
    float*    pb     = (float*)   (base);                 // 25,600,000
    float4*   xyz    = (float4*)  (base + 25600000);      //  1,600,000
    int*      row    = (int*)     (base + 27200000);      //    400,016
    int*      cnt    = (int*)     (base + 27600016);      //    400,000
    int*      cursor = (int*)     (base + 28000016);      //    400,000
    int*      bsum   = (int*)     (base + 28400016);      //        560 (pad)
    unsigned* rec    = (unsigned*)(base + 28400576);      // 51,200,000
    // B^T bf16 hi/lo scratch aliases the head of rec (49,152 B).
    // Safe: k_node_mfma (reader) completes before k_prep (writer) on the stream.
    short*    btw    = (short*)rec;

    hipMemsetAsync(cnt, 0, N_NODES * sizeof(int), stream);

    k_wprep   <<<48, 256, 0, stream>>>(w_s, w_n, btw);
    k_node_mfma<<<(N_NODES + 63) / 64, 256, 0, stream>>>(feat, btw, out, pb, xyz);
    k_hist    <<<(N_EDGES + 255) / 256, 256, 0, stream>>>(src, cnt);
    k_scan_blk<<<SCAN_BLOCKS, 256, 0, stream>>>(cnt, row, bsum);
    k_scan_top<<<1, 128, 0, stream>>>(bsum, row);
    k_scan_add<<<SCAN_BLOCKS, 256, 0, stream>>>(row, cursor, bsum);
    k_prep    <<<(N_EDGES + 255) / 256, 256, 0, stream>>>(src, dstv, bond, xyz,
                                                          cursor, rec);
    k_gather  <<<(N_NODES * 64 + 255) / 256, 256, 0, stream>>>(row, rec, w_n, pb,
                                                               xyz, out);
}

// Round 5
// 316.020 us; speedup vs baseline: 1.1992x; 1.0321x over previous
//
#include <hip/hip_runtime.h>

#define N_NODES 100000
#define N_EDGES 800000
#define NF 81
#define NB 22
#define OC 64
#define SCAN_CHUNK 1024
#define SCAN_BLOCKS ((N_NODES + SCAN_CHUNK - 1) / SCAN_CHUNK)   // 98

typedef __attribute__((ext_vector_type(8))) short bf16x8;
typedef __attribute__((ext_vector_type(4))) float f32x4;

#if defined(__has_builtin)
#if __has_builtin(__builtin_amdgcn_fdot2_f32_bf16)
#define HAVE_FDOT2 1
#endif
#endif

#ifdef HAVE_FDOT2
typedef __attribute__((ext_vector_type(2))) __bf16 bfv2;
#endif

// dot2: c += lo(a)*lo(b) + hi(a)*hi(b), operands are packed bf16 pairs
__device__ inline float dot2b(unsigned a, unsigned b, float c) {
#ifdef HAVE_FDOT2
    return __builtin_amdgcn_fdot2_f32_bf16(__builtin_bit_cast(bfv2, a),
                                           __builtin_bit_cast(bfv2, b), c, false);
#else
    return c + __uint_as_float(a << 16)         * __uint_as_float(b << 16)
             + __uint_as_float(a & 0xffff0000u) * __uint_as_float(b & 0xffff0000u);
#endif
}

// round-to-nearest-even fp32 -> bf16 (high part), returns residual in rest
__device__ inline unsigned short bfsplit(float v, float& rest) {
    const unsigned b = __float_as_uint(v);
    const unsigned short h = (unsigned short)((b + 0x7fffu + ((b >> 16) & 1u)) >> 16);
    rest = v - __uint_as_float(((unsigned)h) << 16);
    return h;
}

// ---------------------------------------------------------------------------
// Build B^T in bf16 hi/lo: BT[c][k], c in [0,128), k in [0,96).
// Written into scratch aliasing the head of the recA region (stream-ordered:
// k_prep overwrites recA only after k_node_mfma has consumed B^T).
__global__ void k_wprep(const float* __restrict__ w_s, const float* __restrict__ w_n,
                        short* __restrict__ bt)
{
    const int tid = blockIdx.x * blockDim.x + threadIdx.x;
    if (tid >= 128 * 96) return;
    const int c = tid / 96;
    const int k = tid - c * 96;
    float v = 0.f;
    if (k < NF) v = (c < OC) ? w_s[k * OC + c] : w_n[k * OC + (c - OC)];
    float rest, dummy;
    const unsigned short h = bfsplit(v, rest);
    const unsigned short l = bfsplit(rest, dummy);
    bt[c * 96 + k]               = (short)h;          // BT_hi
    bt[128 * 96 + c * 96 + k]    = (short)l;          // BT_lo
}

// ---------------------------------------------------------------------------
// Node GEMM on matrix cores: [out | pb] = feat @ [w_s | w_n[:81]]
// Split-bf16 3-pass MFMA (Ah*Bh + Ah*Bl + Al*Bh) -> ~2^-17 relative error.
__global__ __launch_bounds__(256) void k_node_mfma(
    const float* __restrict__ feat, const short* __restrict__ bt,
    float* __restrict__ out, float* __restrict__ pb, float4* __restrict__ xyz)
{
    __shared__ short shA[2 * 64 * 104];               // hi at 0, lo at 6656 (26.6 KB)
    const int t    = threadIdx.x;
    const int lane = t & 63;
    const int w    = t >> 6;
    const int n0   = blockIdx.x * 64;

    // ---- B fragments from global B^T (L2-resident, 16B-aligned b128 loads)
    const int krow = (lane >> 4) * 8;                 // k offset within 32-k tile
    bf16x8 Bh[3][2], Bl[3][2];
#pragma unroll
    for (int kt = 0; kt < 3; ++kt)
#pragma unroll
        for (int c = 0; c < 2; ++c) {
            const int col = w * 32 + c * 16 + (lane & 15);
            const int off = col * 96 + kt * 32 + krow;
            Bh[kt][c] = *(const bf16x8*)(bt + off);
            Bl[kt][c] = *(const bf16x8*)(bt + 128 * 96 + off);
        }

    // ---- stage A (64 rows x 81 k) as bf16 hi/lo into LDS
    const long gbase = (long)n0 * NF;
    const long gmax  = (long)N_NODES * NF;
    for (int j = t; j < (64 * NF) / 4; j += 256) {    // 1296 float4s
        const int flat = j * 4;
        float v[4];
        if (gbase + flat + 3 < gmax) {
            const float4 q = *(const float4*)(feat + gbase + flat);
            v[0] = q.x; v[1] = q.y; v[2] = q.z; v[3] = q.w;
        } else {
#pragma unroll
            for (int i = 0; i < 4; ++i)
                v[i] = (gbase + flat + i < gmax) ? feat[gbase + flat + i] : 0.f;
        }
#pragma unroll
        for (int i = 0; i < 4; ++i) {
            const int fi  = flat + i;
            const int row = (int)((unsigned)fi / 81u);
            const int k   = fi - row * 81;
            float rest, dummy;
            const unsigned short h = bfsplit(v[i], rest);
            const unsigned short l = bfsplit(rest, dummy);
            shA[row * 104 + k]        = (short)h;
            shA[6656 + row * 104 + k] = (short)l;
        }
    }
    // zero K padding 81..96 (frags read up to k=95)
    for (int j = t; j < 64 * 16; j += 256) {
        const int row = j >> 4, k = NF + (j & 15);
        shA[row * 104 + k] = 0;
        shA[6656 + row * 104 + k] = 0;
    }

    // xyz in exact fp32 (distance path must stay fp32-accurate)
    if (t < 64 && n0 + t < N_NODES) {
        const float* fp = feat + (long)(n0 + t) * NF;
        xyz[n0 + t] = make_float4(fp[0], fp[1], fp[2], 0.f);
    }
    __syncthreads();

    // ---- MFMA: 4 row-tiles x 2 col-tiles x 3 k-tiles x 3 passes
    f32x4 acc[4][2];
#pragma unroll
    for (int rt = 0; rt < 4; ++rt)
#pragma unroll
        for (int c = 0; c < 2; ++c)
            acc[rt][c] = (f32x4){0.f, 0.f, 0.f, 0.f};

#pragma unroll
    for (int kt = 0; kt < 3; ++kt) {
        bf16x8 Ah[4], Al[4];
#pragma unroll
        for (int rt = 0; rt < 4; ++rt) {
            const int o = (rt * 16 + (lane & 15)) * 104 + kt * 32 + krow;
            Ah[rt] = *(const bf16x8*)(shA + o);
            Al[rt] = *(const bf16x8*)(shA + 6656 + o);
        }
#pragma unroll
        for (int rt = 0; rt < 4; ++rt)
#pragma unroll
            for (int c = 0; c < 2; ++c) {
                f32x4 a = acc[rt][c];
                a = __builtin_amdgcn_mfma_f32_16x16x32_bf16(Ah[rt], Bh[kt][c], a, 0, 0, 0);
                a = __builtin_amdgcn_mfma_f32_16x16x32_bf16(Ah[rt], Bl[kt][c], a, 0, 0, 0);
                a = __builtin_amdgcn_mfma_f32_16x16x32_bf16(Al[rt], Bh[kt][c], a, 0, 0, 0);
                acc[rt][c] = a;
            }
    }

    // ---- epilogue: D layout col=lane&15, row=(lane>>4)*4+reg (verified map)
    const int c0    = w * 32 + (lane & 15);
    float* db       = (w < 2) ? out : pb;
    const int cbase = (w < 2) ? c0 : c0 - OC;
    const int r0    = (lane >> 4) * 4;
#pragma unroll
    for (int rt = 0; rt < 4; ++rt)
#pragma unroll
        for (int c = 0; c < 2; ++c)
#pragma unroll
            for (int reg = 0; reg < 4; ++reg) {
                const int node = n0 + rt * 16 + r0 + reg;
                if (node < N_NODES)
                    db[(long)node * OC + cbase + c * 16] = acc[rt][c][reg];
            }
}

// ---------------------------------------------------------------------------
// Histogram + rank capture: rank[e] = arrival index of edge e within src[e].
// The atomic moves HERE (coalesced context) so k_prep's chain has no atomic.
__global__ void k_hist(const int* __restrict__ src, int* __restrict__ cnt,
                       int* __restrict__ rank) {
    const int e = blockIdx.x * blockDim.x + threadIdx.x;
    if (e < N_EDGES) rank[e] = atomicAdd(&cnt[src[e]], 1);
}

__global__ __launch_bounds__(256) void k_scan_blk(
    const int* __restrict__ cnt, int* __restrict__ row, int* __restrict__ bsum)
{
    __shared__ int sh[256];
    const int t = threadIdx.x;
    const int base = blockIdx.x * SCAN_CHUNK + t * 4;
    int c0 = 0, c1 = 0, c2 = 0, c3 = 0;
    if (base + 3 < N_NODES) {
        const int4 c = *(const int4*)(cnt + base);
        c0 = c.x; c1 = c.y; c2 = c.z; c3 = c.w;
    } else {
        if (base + 0 < N_NODES) c0 = cnt[base + 0];
        if (base + 1 < N_NODES) c1 = cnt[base + 1];
        if (base + 2 < N_NODES) c2 = cnt[base + 2];
    }
    const int s = c0 + c1 + c2 + c3;
    sh[t] = s;
    __syncthreads();
    for (int off = 1; off < 256; off <<= 1) {
        int v = sh[t];
        int a = (t >= off) ? sh[t - off] : 0;
        __syncthreads();
        sh[t] = v + a;
        __syncthreads();
    }
    const int excl = sh[t] - s;
    if (t == 255) bsum[blockIdx.x] = sh[255];
    if (base + 3 < N_NODES) {
        int4 r;
        r.x = excl; r.y = excl + c0; r.z = excl + c0 + c1; r.w = excl + c0 + c1 + c2;
        *(int4*)(row + base) = r;
    } else {
        int e = excl;
        if (base + 0 < N_NODES) { row[base + 0] = e; e += c0; }
        if (base + 1 < N_NODES) { row[base + 1] = e; e += c1; }
        if (base + 2 < N_NODES) { row[base + 2] = e; }
    }
}

__global__ void k_scan_top(int* __restrict__ bsum, int* __restrict__ row) {
    __shared__ int sh[128];
    const int t = threadIdx.x;
    const int v = (t < SCAN_BLOCKS) ? bsum[t] : 0;
    sh[t] = v;
    __syncthreads();
    for (int off = 1; off < 128; off <<= 1) {
        int x = sh[t];
        int a = (t >= off) ? sh[t - off] : 0;
        __syncthreads();
        sh[t] = x + a;
        __syncthreads();
    }
    if (t < SCAN_BLOCKS) bsum[t] = sh[t] - v;
    if (t == 127) row[N_NODES] = sh[127];
}

__global__ __launch_bounds__(256) void k_scan_add(
    int* __restrict__ row, const int* __restrict__ bsum)
{
    const int off = bsum[blockIdx.x];
    const int base = blockIdx.x * SCAN_CHUNK + threadIdx.x * 4;
    if (base + 3 < N_NODES) {
        int4 r = *(const int4*)(row + base);
        r.x += off; r.y += off; r.z += off; r.w += off;
        *(int4*)(row + base) = r;
    } else {
#pragma unroll
        for (int k = 0; k < 4; ++k)
            if (base + k < N_NODES)
                row[base + k] += off;
    }
}

// ---------------------------------------------------------------------------
// Scatter records into src-sorted slots. pos = row[src] + rank[e] (NO atomic).
// recA[pos*12 + 0..10] = bond bf16 pairs, [11] = inv (f32). recB[pos] = dst.
// 4 edges per thread (e, e+256, e+512, e+768) -> 4 independent chains.
__device__ inline unsigned pk_bf16(float a, float b) {
    const unsigned ua = (__float_as_uint(a) + 0x8000u) >> 16;
    const unsigned ub = (__float_as_uint(b) + 0x8000u) & 0xffff0000u;
    return ua | ub;
}

__global__ __launch_bounds__(256) void k_prep(
    const int* __restrict__ src, const int* __restrict__ dst,
    const float* __restrict__ bond, const float4* __restrict__ xyz,
    const int* __restrict__ row, const int* __restrict__ rank,
    unsigned* __restrict__ recA, unsigned* __restrict__ recB)
{
    const int base = blockIdx.x * 1024 + threadIdx.x;
    bool ok[4];
    int e[4], s[4], d[4], pos[4];
#pragma unroll
    for (int u = 0; u < 4; ++u) {
        e[u]  = base + u * 256;
        ok[u] = e[u] < N_EDGES;
    }
    // ids (coalesced) + rank (coalesced)
#pragma unroll
    for (int u = 0; u < 4; ++u)
        if (ok[u]) { s[u] = src[e[u]]; d[u] = dst[e[u]]; }
    int rk[4];
#pragma unroll
    for (int u = 0; u < 4; ++u)
        if (ok[u]) rk[u] = rank[e[u]];
    // xyz gathers (L2-resident) - issue all 8 before use
    float4 xa[4], xb[4];
#pragma unroll
    for (int u = 0; u < 4; ++u)
        if (ok[u]) { xa[u] = xyz[s[u]]; xb[u] = xyz[d[u]]; }
    // pos = row[s] + rank (row is L2-resident)
#pragma unroll
    for (int u = 0; u < 4; ++u)
        if (ok[u]) pos[u] = row[s[u]] + rk[u];
    // inv
    float inv[4];
#pragma unroll
    for (int u = 0; u < 4; ++u) {
        const float dx = xa[u].x - xb[u].x, dy = xa[u].y - xb[u].y,
                    dz = xa[u].z - xb[u].z;
        const float d2 = dx * dx + dy * dy + dz * dz;
        inv[u] = (d2 > 0.f) ? __builtin_amdgcn_rcpf(d2) : 1.0e4f;
    }
    // bond loads: all 4 edges issued before packing (MLP)
    float2 bv[4][11];
#pragma unroll
    for (int u = 0; u < 4; ++u)
        if (ok[u]) {
            const float2* bp = (const float2*)(bond + (long)e[u] * NB);
#pragma unroll
            for (int j = 0; j < 11; ++j) bv[u][j] = bp[j];
        }
    // pack + scattered record stores
#pragma unroll
    for (int u = 0; u < 4; ++u) {
        if (!ok[u]) continue;
        unsigned p[11];
#pragma unroll
        for (int j = 0; j < 11; ++j) p[j] = pk_bf16(bv[u][j].x, bv[u][j].y);
        unsigned* a = recA + (size_t)pos[u] * 12;
        *(uint4*)(a)     = make_uint4(p[0], p[1], p[2], p[3]);
        *(uint4*)(a + 4) = make_uint4(p[4], p[5], p[6], p[7]);
        *(uint4*)(a + 8) = make_uint4(p[8], p[9], p[10], __float_as_uint(inv[u]));
        recB[pos[u]] = (unsigned)d[u];
    }
}

// ---------------------------------------------------------------------------
// Gather: wave per node, lane = channel, NO atomics.
// 4-edge unroll + dot2 bf16 math. inv is recA dword 11; dst in recB.
__global__ __launch_bounds__(256) void k_gather(
    const int* __restrict__ row, const unsigned* __restrict__ recA,
    const unsigned* __restrict__ recB, const float* __restrict__ w_n,
    const float* __restrict__ pb, const float4* __restrict__ xyz,
    float* __restrict__ out)
{
    const int lane = threadIdx.x & 63;
    const int wid  = (int)((blockIdx.x * blockDim.x + threadIdx.x) >> 6);
    if (wid >= N_NODES) return;
    const int n = __builtin_amdgcn_readfirstlane(wid);

    // per-lane w_n bond columns, packed as bf16 pairs (matches record packing)
    unsigned wp[11];
#pragma unroll
    for (int j = 0; j < 11; ++j)
        wp[j] = pk_bf16(w_n[(NF + 2 * j) * OC + lane],
                        w_n[(NF + 2 * j + 1) * OC + lane]);
    const float w0 = w_n[0 * OC + lane];
    const float w1 = w_n[1 * OC + lane];
    const float w2 = w_n[2 * OC + lane];

    const int rs = row[n], re = row[n + 1];
    const float4 xs = xyz[n];
    const float pa = pb[(long)n * OC + lane]
                   - (xs.x * w0 + xs.y * w1 + xs.z * w2);

    float acc = 0.f;
    int i = rs;

    // ---- main loop: 4 edges in flight
    for (; i + 4 <= re; i += 4) {
        unsigned P[4][12];
        unsigned db[4];
#pragma unroll
        for (int u = 0; u < 4; ++u) {
            const unsigned* r = recA + (size_t)(i + u) * 12;
#pragma unroll
            for (int j = 0; j < 12; ++j) P[u][j] = r[j];
            db[u] = recB[i + u];
        }
        float pbt[4];
#pragma unroll
        for (int u = 0; u < 4; ++u)
            pbt[u] = pb[(long)(int)db[u] * OC + lane];
        float c[4];
#pragma unroll
        for (int u = 0; u < 4; ++u)
            c[u] = __uint_as_float(P[u][11]) * (pa + pbt[u]);
#pragma unroll
        for (int j = 0; j < 11; ++j)
#pragma unroll
            for (int u = 0; u < 4; ++u)
                c[u] = dot2b(P[u][j], wp[j], c[u]);
        acc += (c[0] + c[1]) + (c[2] + c[3]);
    }

    // ---- tail: one edge at a time
    for (; i < re; ++i) {
        const unsigned* r = recA + (size_t)i * 12;
        unsigned p[12];
#pragma unroll
        for (int j = 0; j < 12; ++j) p[j] = r[j];
        const unsigned dbt = recB[i];
        const float pbt = pb[(long)(int)dbt * OC + lane];
        float c = __uint_as_float(p[11]) * (pa + pbt);
#pragma unroll
        for (int j = 0; j < 11; ++j)
            c = dot2b(p[j], wp[j], c);
        acc += c;
    }

    out[(long)n * OC + lane] += acc;
}

// ---------------------------------------------------------------------------
extern "C" void kernel_launch(void* const* d_in, const int* in_sizes, int n_in,
                              void* d_out, int out_size, void* d_ws, size_t ws_size,
                              hipStream_t stream) {
    const float* feat = (const float*)d_in[0];
    const float* bond = (const float*)d_in[1];
    const float* w_s  = (const float*)d_in[2];
    const float* w_n  = (const float*)d_in[3];
    const int*   src  = (const int*)d_in[4];
    const int*   dstv = (const int*)d_in[5];
    float* out = (float*)d_out;

    // workspace layout (16B-aligned), ~72.8 MB total
    char* base = (char*)d_ws;
    float*    pb     = (float*)   (base);                 // 25,600,000
    float4*   xyz    = (float4*)  (base + 25600000);      //  1,600,000
    int*      row    = (int*)     (base + 27200000);      //    400,016
    int*      cnt    = (int*)     (base + 27600016);      //    400,000
    int*      rank   = (int*)     (base + 28000016);      //  3,200,000
    int*      bsum   = (int*)     (base + 31200016);      //        560 (pad)
    unsigned* recA   = (unsigned*)(base + 31200640);      // 38,400,000 (48B/edge)
    unsigned* recB   = (unsigned*)(base + 69600640);      //  3,200,000 (dst ids)
    // B^T bf16 hi/lo scratch aliases the head of recA (49,152 B).
    // Safe: k_node_mfma (reader) completes before k_prep (writer) on the stream.
    short*    btw    = (short*)recA;

    hipMemsetAsync(cnt, 0, N_NODES * sizeof(int), stream);

    k_wprep   <<<48, 256, 0, stream>>>(w_s, w_n, btw);
    k_node_mfma<<<(N_NODES + 63) / 64, 256, 0, stream>>>(feat, btw, out, pb, xyz);
    k_hist    <<<(N_EDGES + 255) / 256, 256, 0, stream>>>(src, cnt, rank);
    k_scan_blk<<<SCAN_BLOCKS, 256, 0, stream>>>(cnt, row, bsum);
    k_scan_top<<<1, 128, 0, stream>>>(bsum, row);
    k_scan_add<<<SCAN_BLOCKS, 256, 0, stream>>>(row, bsum);
    k_prep    <<<(N_EDGES + 1023) / 1024, 256, 0, stream>>>(src, dstv, bond, xyz,
                                                            row, rank, recA, recB);
    k_gather  <<<(N_NODES * 64 + 255) / 256, 256, 0, stream>>>(row, recA, recB,
                                                               w_n, pb, xyz, out);
}